// Round 5
// baseline (392.161 us; speedup 1.0000x reference)
//
#include <hip/hip_runtime.h>
#include <hip/hip_bf16.h>

// Problem: B=16, N=4096, D=768, M=8
//   xn = LayerNorm(x) * gamma + beta          [B,N,D]
//   sim = (queries @ xn^T) * D^-0.5           [B,M,N]
//   attn = softmax(sim, axis=-1)
//   out = attn @ xn                           [B,M,D]
// All I/O fp32. Compute fp32.

#define B_ 16
#define N_ 4096
#define D_ 768
#define M_ 8
#define EPS_ 1e-3f
#define SCALE_ 0.03608439182435161f  // 768^-0.5

// ws layout (floats)
#define SIM_OFF   0            // B*M*N = 524288 floats
#define MEAN_OFF  524288       // B*N   =  65536
#define RSTD_OFF  589824       // B*N   =  65536
#define SMAX_OFF  655360       // B*M   =    128
#define SINV_OFF  655488       // B*M   =    128

// ---------------- kernel 1: LayerNorm stats + sim = q . xn ----------------
// one wave per row; lane owns 12 cols (3 float4). Stats: 12-swizzle butterfly
// (all lanes need mean). Sim accs: thinning reduction, 10 swizzles for 8 values.
__global__ __launch_bounds__(256) void k_ln_sim(
    const float* __restrict__ x,
    const float* __restrict__ q,
    const float* __restrict__ gm,
    const float* __restrict__ bt,
    float* __restrict__ sim, float* __restrict__ meanb, float* __restrict__ rstdb)
{
    const int lane = threadIdx.x & 63;
    const int gw   = blockIdx.x * 4 + (threadIdx.x >> 6);
    const int total_waves = gridDim.x * 4;

    float g[12], bb[12], qr[8][12];
#pragma unroll
    for (int i = 0; i < 3; i++) {
        const int c4 = (lane + i * 64) * 4;
        float4 gv = *(const float4*)(gm + c4);
        float4 bv = *(const float4*)(bt + c4);
        g[i * 4 + 0] = gv.x; g[i * 4 + 1] = gv.y; g[i * 4 + 2] = gv.z; g[i * 4 + 3] = gv.w;
        bb[i * 4 + 0] = bv.x; bb[i * 4 + 1] = bv.y; bb[i * 4 + 2] = bv.z; bb[i * 4 + 3] = bv.w;
#pragma unroll
        for (int m = 0; m < 8; m++) {
            float4 qv = *(const float4*)(q + m * D_ + c4);
            qr[m][i * 4 + 0] = qv.x; qr[m][i * 4 + 1] = qv.y;
            qr[m][i * 4 + 2] = qv.z; qr[m][i * 4 + 3] = qv.w;
        }
    }

    const bool hi32 = (lane & 32) != 0;
    const bool hi16 = (lane & 16) != 0;
    const bool hi8  = (lane & 8)  != 0;

    for (int row = gw; row < B_ * N_; row += total_waves) {
        const float* xr = x + (size_t)row * D_;
        float v[12];
#pragma unroll
        for (int i = 0; i < 3; i++) {
            float4 p = *(const float4*)(xr + (lane + i * 64) * 4);
            v[i * 4 + 0] = p.x; v[i * 4 + 1] = p.y;
            v[i * 4 + 2] = p.z; v[i * 4 + 3] = p.w;
        }
        float s = 0.f, s2 = 0.f;
#pragma unroll
        for (int k = 0; k < 12; k++) { s += v[k]; s2 += v[k] * v[k]; }
#pragma unroll
        for (int mask = 32; mask; mask >>= 1) {
            s  += __shfl_xor(s,  mask, 64);
            s2 += __shfl_xor(s2, mask, 64);
        }
        const float mean = s * (1.0f / 768.0f);
        float var = s2 * (1.0f / 768.0f) - mean * mean;
        var = fmaxf(var, 0.0f);
        const float rstd = rsqrtf(var + EPS_);

        float acc[8];
#pragma unroll
        for (int m = 0; m < 8; m++) acc[m] = 0.f;
#pragma unroll
        for (int k = 0; k < 12; k++) {
            const float xn = (v[k] - mean) * rstd * g[k] + bb[k];
#pragma unroll
            for (int m = 0; m < 8; m++) acc[m] = fmaf(qr[m][k], xn, acc[m]);
        }

        // thinning reduction: 8 values over 64 lanes -> lane octet (lane>>3)==m
        // stage A (xor 32): keep 4, send 4
        float a0 = hi32 ? acc[4] : acc[0], sA0 = hi32 ? acc[0] : acc[4];
        float a1 = hi32 ? acc[5] : acc[1], sA1 = hi32 ? acc[1] : acc[5];
        float a2 = hi32 ? acc[6] : acc[2], sA2 = hi32 ? acc[2] : acc[6];
        float a3 = hi32 ? acc[7] : acc[3], sA3 = hi32 ? acc[3] : acc[7];
        a0 += __shfl_xor(sA0, 32, 64);
        a1 += __shfl_xor(sA1, 32, 64);
        a2 += __shfl_xor(sA2, 32, 64);
        a3 += __shfl_xor(sA3, 32, 64);
        // stage B (xor 16): keep 2, send 2   (m = bit5*4 + bit4*2 + j)
        float b0 = hi16 ? a2 : a0, sB0 = hi16 ? a0 : a2;
        float b1 = hi16 ? a3 : a1, sB1 = hi16 ? a1 : a3;
        b0 += __shfl_xor(sB0, 16, 64);
        b1 += __shfl_xor(sB1, 16, 64);
        // stage C (xor 8): keep 1, send 1    (m = bit5*4 + bit4*2 + bit3 = lane>>3)
        float c0 = hi8 ? b1 : b0, sC0 = hi8 ? b0 : b1;
        c0 += __shfl_xor(sC0, 8, 64);
        // stage D: reduce within octet
        c0 += __shfl_xor(c0, 4, 64);
        c0 += __shfl_xor(c0, 2, 64);
        c0 += __shfl_xor(c0, 1, 64);

        const int b = row >> 12, n = row & (N_ - 1);
        if (lane == 0) {
            meanb[row] = mean;
            rstdb[row] = rstd;
        }
        if ((lane & 7) == 0) {
            const int m = lane >> 3;
            sim[(size_t)((b * 8 + m) << 12) + n] = c0 * SCALE_;
        }
    }
}

// ---------------- kernel 2: per-(b,m) softmax max and 1/sum; zero out ----------------
__global__ __launch_bounds__(256) void k_stats(
    const float* __restrict__ sim, float* __restrict__ smax, float* __restrict__ sinv,
    float* __restrict__ out0)
{
    const float* p = sim + (size_t)blockIdx.x * N_;   // blockIdx 0..127 = b*8+m
    const int t = threadIdx.x;
    const int lane = t & 63, wave = t >> 6;
    __shared__ float red[4];

    // fold: zero the output accumulator (B*M*D = 98304 = 3 * 128*256)
    const int gid = blockIdx.x * 256 + t;
    out0[gid] = 0.f; out0[gid + 32768] = 0.f; out0[gid + 65536] = 0.f;

    float v[16];
    float mx = -3.4e38f;
#pragma unroll
    for (int i = 0; i < 16; i++) { v[i] = p[t + i * 256]; mx = fmaxf(mx, v[i]); }
#pragma unroll
    for (int mask = 32; mask; mask >>= 1) mx = fmaxf(mx, __shfl_xor(mx, mask, 64));
    if (lane == 0) red[wave] = mx;
    __syncthreads();
    mx = fmaxf(fmaxf(red[0], red[1]), fmaxf(red[2], red[3]));
    __syncthreads();

    float s = 0.f;
#pragma unroll
    for (int i = 0; i < 16; i++) s += __expf(v[i] - mx);
#pragma unroll
    for (int mask = 32; mask; mask >>= 1) s += __shfl_xor(s, mask, 64);
    if (lane == 0) red[wave] = s;
    __syncthreads();
    if (t == 0) {
        s = red[0] + red[1] + red[2] + red[3];
        smax[blockIdx.x] = mx;
        sinv[blockIdx.x] = 1.0f / s;
    }
}

// ---------------- kernel 3: out += attn @ xn (recompute xn) ----------------
// grid: 16 b * 64 chunks of 64 rows = 1024 blocks; 192 threads (3 waves);
// thread owns cols 4t..4t+3 via float4 loads.
__global__ __launch_bounds__(192) void k_out(
    const float* __restrict__ x,
    const float* __restrict__ gm,
    const float* __restrict__ bt,
    const float* __restrict__ sim,
    const float* __restrict__ meanb,
    const float* __restrict__ rstdb,
    const float* __restrict__ smax,
    const float* __restrict__ sinv,
    float* __restrict__ out)
{
    __shared__ float w_s[8 * 64];
    __shared__ float mean_s[64];
    __shared__ float rstd_s[64];

    const int b = blockIdx.x >> 6;
    const int n0 = (blockIdx.x & 63) * 64;
    const int t = threadIdx.x;   // 0..191

    for (int idx = t; idx < 8 * 64; idx += 192) {
        const int m = idx >> 6, nn = idx & 63;
        const float v = sim[(size_t)((b * 8 + m) << 12) + n0 + nn];
        w_s[idx] = __expf(v - smax[b * 8 + m]) * sinv[b * 8 + m];
    }
    if (t < 64) {
        mean_s[t] = meanb[b * N_ + n0 + t];
        rstd_s[t] = rstdb[b * N_ + n0 + t];
    }
    __syncthreads();

    const int c4 = t * 4;
    const float4 g4 = *(const float4*)(gm + c4);
    const float4 b4 = *(const float4*)(bt + c4);

    float acc[8][4];
#pragma unroll
    for (int m = 0; m < 8; m++)
#pragma unroll
        for (int j = 0; j < 4; j++) acc[m][j] = 0.f;

    const float* xb = x + ((size_t)(b * N_ + n0)) * D_;
#pragma unroll 2
    for (int nn = 0; nn < 64; nn++) {
        const float4 xv = *(const float4*)(xb + (size_t)nn * D_ + c4);
        const float mu = mean_s[nn], rs = rstd_s[nn];
        const float xn0 = (xv.x - mu) * rs * g4.x + b4.x;
        const float xn1 = (xv.y - mu) * rs * g4.y + b4.y;
        const float xn2 = (xv.z - mu) * rs * g4.z + b4.z;
        const float xn3 = (xv.w - mu) * rs * g4.w + b4.w;
#pragma unroll
        for (int m = 0; m < 8; m++) {
            const float a = w_s[m * 64 + nn];
            acc[m][0] = fmaf(a, xn0, acc[m][0]);
            acc[m][1] = fmaf(a, xn1, acc[m][1]);
            acc[m][2] = fmaf(a, xn2, acc[m][2]);
            acc[m][3] = fmaf(a, xn3, acc[m][3]);
        }
    }

    // rotate m-order per block to spread atomic contention
#pragma unroll
    for (int mm = 0; mm < 8; mm++) {
        const int m = (mm + (blockIdx.x & 7)) & 7;
        float* o = out + (size_t)(b * 8 + m) * D_ + c4;
        atomicAdd(o + 0, acc[m][0]);
        atomicAdd(o + 1, acc[m][1]);
        atomicAdd(o + 2, acc[m][2]);
        atomicAdd(o + 3, acc[m][3]);
    }
}

extern "C" void kernel_launch(void* const* d_in, const int* in_sizes, int n_in,
                              void* d_out, int out_size, void* d_ws, size_t ws_size,
                              hipStream_t stream)
{
    const float* x  = (const float*)d_in[0];
    const float* q  = (const float*)d_in[1];
    const float* gm = (const float*)d_in[2];
    const float* bt = (const float*)d_in[3];
    float* out = (float*)d_out;

    float* ws    = (float*)d_ws;
    float* sim   = ws + SIM_OFF;
    float* meanb = ws + MEAN_OFF;
    float* rstdb = ws + RSTD_OFF;
    float* smax  = ws + SMAX_OFF;
    float* sinv  = ws + SINV_OFF;

    k_ln_sim<<<2048, 256, 0, stream>>>(x, q, gm, bt, sim, meanb, rstdb);
    k_stats<<<B_ * M_, 256, 0, stream>>>(sim, smax, sinv, out);
    k_out<<<B_ * 64, 192, 0, stream>>>(x, gm, bt, sim, meanb, rstdb, smax, sinv, out);
}

// Round 6
// 329.356 us; speedup vs baseline: 1.1907x; 1.1907x over previous
//
#include <hip/hip_runtime.h>
#include <hip/hip_bf16.h>

// Problem: B=16, N=4096, D=768, M=8
//   xn = LayerNorm(x) * gamma + beta          [B,N,D]
//   sim = (queries @ xn^T) * D^-0.5           [B,M,N]
//   attn = softmax(sim, axis=-1)
//   out = attn @ xn                           [B,M,D]
// All I/O fp32. Compute fp32.

#define B_ 16
#define N_ 4096
#define D_ 768
#define M_ 8
#define EPS_ 1e-3f
#define SCALE_ 0.03608439182435161f  // 768^-0.5

// ws layout (floats)
#define SIM_OFF   0            // B*M*N = 524288 floats
#define MEAN_OFF  524288       // B*N   =  65536
#define RSTD_OFF  589824       // B*N   =  65536
#define SMAX_OFF  655360       // B*M   =    128
#define SINV_OFF  655488       // B*M   =    128

// ---------------- kernel 1: LayerNorm stats + sim = q . xn ----------------
// one wave per row; lane owns 12 cols (3 float4).
// gamma folded into q: sim_m = SCALE*(rs*(dot(qg,v) - mu*qgs_m) + qb_m)
// -> per-row dot is independent of the stats reduction (overlapped), no
//    per-element xn compute, g/b not live in the loop.
__global__ __launch_bounds__(256) void k_ln_sim(
    const float* __restrict__ x,
    const float* __restrict__ q,
    const float* __restrict__ gm,
    const float* __restrict__ bt,
    float* __restrict__ sim, float* __restrict__ meanb, float* __restrict__ rstdb)
{
    const int lane = threadIdx.x & 63;
    const int gw   = blockIdx.x * 4 + (threadIdx.x >> 6);
    const int total_waves = gridDim.x * 4;

    // init: per-lane qg = q*gamma; wave-wide qgs_m = sum(q*g), qb_m = sum(q*b)
    float qg[8][12];
    float qgs[8], qb[8];
#pragma unroll
    for (int m = 0; m < 8; m++) { qgs[m] = 0.f; qb[m] = 0.f; }
#pragma unroll
    for (int i = 0; i < 3; i++) {
        const int c4 = (lane + i * 64) * 4;
        float4 gv = *(const float4*)(gm + c4);
        float4 bv = *(const float4*)(bt + c4);
#pragma unroll
        for (int m = 0; m < 8; m++) {
            float4 qv = *(const float4*)(q + m * D_ + c4);
            qg[m][i * 4 + 0] = qv.x * gv.x;
            qg[m][i * 4 + 1] = qv.y * gv.y;
            qg[m][i * 4 + 2] = qv.z * gv.z;
            qg[m][i * 4 + 3] = qv.w * gv.w;
            qgs[m] += qg[m][i * 4 + 0] + qg[m][i * 4 + 1] + qg[m][i * 4 + 2] + qg[m][i * 4 + 3];
            qb[m]  += qv.x * bv.x + qv.y * bv.y + qv.z * bv.z + qv.w * bv.w;
        }
    }
#pragma unroll
    for (int mask = 32; mask; mask >>= 1)
#pragma unroll
        for (int m = 0; m < 8; m++) {
            qgs[m] += __shfl_xor(qgs[m], mask, 64);
            qb[m]  += __shfl_xor(qb[m],  mask, 64);
        }
    // pre-select this lane's octet values (m = lane>>3) via static tree
    const int mo = lane >> 3;
    const float qgs_sel =
        (mo & 4) ? ((mo & 2) ? ((mo & 1) ? qgs[7] : qgs[6]) : ((mo & 1) ? qgs[5] : qgs[4]))
                 : ((mo & 2) ? ((mo & 1) ? qgs[3] : qgs[2]) : ((mo & 1) ? qgs[1] : qgs[0]));
    const float qbs = SCALE_ *
        ((mo & 4) ? ((mo & 2) ? ((mo & 1) ? qb[7] : qb[6]) : ((mo & 1) ? qb[5] : qb[4]))
                  : ((mo & 2) ? ((mo & 1) ? qb[3] : qb[2]) : ((mo & 1) ? qb[1] : qb[0])));

    const bool hi32 = (lane & 32) != 0;
    const bool hi16 = (lane & 16) != 0;
    const bool hi8  = (lane & 8)  != 0;

    for (int row = gw; row < B_ * N_; row += total_waves) {
        const float* xr = x + (size_t)row * D_;
        float v[12];
#pragma unroll
        for (int i = 0; i < 3; i++) {
            float4 p = *(const float4*)(xr + (lane + i * 64) * 4);
            v[i * 4 + 0] = p.x; v[i * 4 + 1] = p.y;
            v[i * 4 + 2] = p.z; v[i * 4 + 3] = p.w;
        }
        // stats partials and dot partials — independent chains
        float s = 0.f, s2 = 0.f;
#pragma unroll
        for (int k = 0; k < 12; k++) { s += v[k]; s2 += v[k] * v[k]; }
        float acc[8];
#pragma unroll
        for (int m = 0; m < 8; m++) acc[m] = 0.f;
#pragma unroll
        for (int k = 0; k < 12; k++)
#pragma unroll
            for (int m = 0; m < 8; m++) acc[m] = fmaf(qg[m][k], v[k], acc[m]);

        // stats: full butterfly (all lanes need mean/rstd)
#pragma unroll
        for (int mask = 32; mask; mask >>= 1) {
            s  += __shfl_xor(s,  mask, 64);
            s2 += __shfl_xor(s2, mask, 64);
        }
        const float mean = s * (1.0f / 768.0f);
        float var = s2 * (1.0f / 768.0f) - mean * mean;
        var = fmaxf(var, 0.0f);
        const float rstd = rsqrtf(var + EPS_);

        // dot: thinning reduction, 8 values -> lane octet (lane>>3)==m
        float a0 = hi32 ? acc[4] : acc[0], sA0 = hi32 ? acc[0] : acc[4];
        float a1 = hi32 ? acc[5] : acc[1], sA1 = hi32 ? acc[1] : acc[5];
        float a2 = hi32 ? acc[6] : acc[2], sA2 = hi32 ? acc[2] : acc[6];
        float a3 = hi32 ? acc[7] : acc[3], sA3 = hi32 ? acc[3] : acc[7];
        a0 += __shfl_xor(sA0, 32, 64);
        a1 += __shfl_xor(sA1, 32, 64);
        a2 += __shfl_xor(sA2, 32, 64);
        a3 += __shfl_xor(sA3, 32, 64);
        float b0 = hi16 ? a2 : a0, sB0 = hi16 ? a0 : a2;
        float b1 = hi16 ? a3 : a1, sB1 = hi16 ? a1 : a3;
        b0 += __shfl_xor(sB0, 16, 64);
        b1 += __shfl_xor(sB1, 16, 64);
        float c0 = hi8 ? b1 : b0, sC0 = hi8 ? b0 : b1;
        c0 += __shfl_xor(sC0, 8, 64);
        c0 += __shfl_xor(c0, 4, 64);
        c0 += __shfl_xor(c0, 2, 64);
        c0 += __shfl_xor(c0, 1, 64);

        const int b = row >> 12, n = row & (N_ - 1);
        if (lane == 0) {
            meanb[row] = mean;
            rstdb[row] = rstd;
        }
        if ((lane & 7) == 0) {
            // sim = SCALE*(rs*(c0 - mu*qgs) + qb)
            sim[(size_t)((b * 8 + mo) << 12) + n] =
                fmaf(rstd * SCALE_, c0 - mean * qgs_sel, qbs);
        }
    }
}

// ---------------- kernel 2: per-(b,m) softmax max and 1/sum; zero out ----------------
__global__ __launch_bounds__(256) void k_stats(
    const float* __restrict__ sim, float* __restrict__ smax, float* __restrict__ sinv,
    float* __restrict__ out0)
{
    const float* p = sim + (size_t)blockIdx.x * N_;   // blockIdx 0..127 = b*8+m
    const int t = threadIdx.x;
    const int lane = t & 63, wave = t >> 6;
    __shared__ float red[4];

    // fold: zero the output accumulator (B*M*D = 98304 = 3 * 128*256)
    const int gid = blockIdx.x * 256 + t;
    out0[gid] = 0.f; out0[gid + 32768] = 0.f; out0[gid + 65536] = 0.f;

    float v[16];
    float mx = -3.4e38f;
#pragma unroll
    for (int i = 0; i < 16; i++) { v[i] = p[t + i * 256]; mx = fmaxf(mx, v[i]); }
#pragma unroll
    for (int mask = 32; mask; mask >>= 1) mx = fmaxf(mx, __shfl_xor(mx, mask, 64));
    if (lane == 0) red[wave] = mx;
    __syncthreads();
    mx = fmaxf(fmaxf(red[0], red[1]), fmaxf(red[2], red[3]));
    __syncthreads();

    float s = 0.f;
#pragma unroll
    for (int i = 0; i < 16; i++) s += __expf(v[i] - mx);
#pragma unroll
    for (int mask = 32; mask; mask >>= 1) s += __shfl_xor(s, mask, 64);
    if (lane == 0) red[wave] = s;
    __syncthreads();
    if (t == 0) {
        s = red[0] + red[1] + red[2] + red[3];
        smax[blockIdx.x] = mx;
        sinv[blockIdx.x] = 1.0f / s;
    }
}

// ---------------- kernel 3: out += attn @ xn (recompute xn) ----------------
// round-4 proven config: 1024 blocks (4/CU, 16 waves/CU), 256 threads,
// thread owns cols t, t+256, t+512 (scalar coalesced), unroll 4.
__global__ __launch_bounds__(256) void k_out(
    const float* __restrict__ x,
    const float* __restrict__ gm,
    const float* __restrict__ bt,
    const float* __restrict__ sim,
    const float* __restrict__ meanb,
    const float* __restrict__ rstdb,
    const float* __restrict__ smax,
    const float* __restrict__ sinv,
    float* __restrict__ out)
{
    __shared__ float w_s[8 * 64];
    __shared__ float mean_s[64];
    __shared__ float rstd_s[64];

    const int b = blockIdx.x >> 6;
    const int n0 = (blockIdx.x & 63) * 64;
    const int t = threadIdx.x;

#pragma unroll
    for (int k = 0; k < 2; k++) {
        const int idx = t + k * 256;              // idx = m*64 + nn
        const int m = idx >> 6, nn = idx & 63;
        const float v = sim[(size_t)((b * 8 + m) << 12) + n0 + nn];
        w_s[idx] = __expf(v - smax[b * 8 + m]) * sinv[b * 8 + m];
    }
    if (t < 64) {
        mean_s[t] = meanb[b * N_ + n0 + t];
        rstd_s[t] = rstdb[b * N_ + n0 + t];
    }
    __syncthreads();

    const float g0 = gm[t],       bb0 = bt[t];
    const float g1 = gm[t + 256], bb1 = bt[t + 256];
    const float g2 = gm[t + 512], bb2 = bt[t + 512];

    float acc[8][3];
#pragma unroll
    for (int m = 0; m < 8; m++)
#pragma unroll
        for (int j = 0; j < 3; j++) acc[m][j] = 0.f;

    const float* xb = x + ((size_t)(b * N_ + n0)) * D_;
#pragma unroll 4
    for (int nn = 0; nn < 64; nn++) {
        const float* xr = xb + (size_t)nn * D_;
        const float mu = mean_s[nn], rs = rstd_s[nn];
        const float xn0 = (xr[t]       - mu) * rs * g0 + bb0;
        const float xn1 = (xr[t + 256] - mu) * rs * g1 + bb1;
        const float xn2 = (xr[t + 512] - mu) * rs * g2 + bb2;
#pragma unroll
        for (int m = 0; m < 8; m++) {
            const float a = w_s[m * 64 + nn];
            acc[m][0] = fmaf(a, xn0, acc[m][0]);
            acc[m][1] = fmaf(a, xn1, acc[m][1]);
            acc[m][2] = fmaf(a, xn2, acc[m][2]);
        }
    }

    // rotate m-order per block to spread atomic contention
#pragma unroll
    for (int mm = 0; mm < 8; mm++) {
        const int m = (mm + (blockIdx.x & 7)) & 7;
        float* o = out + (size_t)(b * 8 + m) * D_;
        atomicAdd(o + t,       acc[m][0]);
        atomicAdd(o + t + 256, acc[m][1]);
        atomicAdd(o + t + 512, acc[m][2]);
    }
}

extern "C" void kernel_launch(void* const* d_in, const int* in_sizes, int n_in,
                              void* d_out, int out_size, void* d_ws, size_t ws_size,
                              hipStream_t stream)
{
    const float* x  = (const float*)d_in[0];
    const float* q  = (const float*)d_in[1];
    const float* gm = (const float*)d_in[2];
    const float* bt = (const float*)d_in[3];
    float* out = (float*)d_out;

    float* ws    = (float*)d_ws;
    float* sim   = ws + SIM_OFF;
    float* meanb = ws + MEAN_OFF;
    float* rstdb = ws + RSTD_OFF;
    float* smax  = ws + SMAX_OFF;
    float* sinv  = ws + SINV_OFF;

    k_ln_sim<<<2048, 256, 0, stream>>>(x, q, gm, bt, sim, meanb, rstdb);
    k_stats<<<B_ * M_, 256, 0, stream>>>(sim, smax, sinv, out);
    k_out<<<B_ * 64, 256, 0, stream>>>(x, gm, bt, sim, meanb, rstdb, smax, sinv, out);
}